// Round 5
// baseline (2545.909 us; speedup 1.0000x reference)
//
#include <hip/hip_runtime.h>
#include <cstdint>
#include <cstddef>

// PCD Align (EDVR) — NHWC split-bf16 pipeline, barrier-free MFMA convs.
// B=4, NF=64, DG=8, K=9. Levels: L3 32x32, L2 64x64, L1 128x128.
// Activations: [B][H][W][64] bf16, hi plane then lo plane (v = hi + lo ~ fp32).
// om tensors:  [B][H][W][216] fp32 (exact offsets for DCN sampling).
// R5 fix: L2_off_b slot moved off F1L2 (was aliasing its lo plane -> absmax 2.0).

typedef __bf16 bf16x8 __attribute__((ext_vector_type(8)));
typedef __bf16 bf16x4 __attribute__((ext_vector_type(4)));
typedef float  f32x4  __attribute__((ext_vector_type(4)));

// -------------------- weight split  [n][OC][C][3][3] -> per conv [9][OCPAD][C] hi,lo --------------------
template<int OCPAD, int C>
__global__ void wsplit_k(const float* __restrict__ src, __bf16* __restrict__ dst,
                         int OC, long total)
{
    const int per = 9 * OCPAD * C;
    long i = (long)blockIdx.x * 256 + threadIdx.x;
    if (i >= total) return;
    int n  = (int)(i / per);
    int r  = (int)(i - (long)n * per);
    int t  = r / (OCPAD * C);
    int r2 = r - t * (OCPAD * C);
    int o  = r2 / C;
    int c  = r2 - o * C;
    float v = (o < OC) ? src[(((long)n * OC + o) * C + c) * 9 + t] : 0.f;
    __bf16 h = (__bf16)v;
    __bf16 l = (__bf16)(v - (float)h);
    __bf16* d = dst + (long)n * 2 * per;
    d[r]       = h;
    d[per + r] = l;
}

// [N][O=64][C=64][9] -> [N][9][64][64]  (k,c,o)  fp32 (for dcn VALU core)
__global__ void transpose_dcnw(const float* __restrict__ w, float* __restrict__ wt, long total)
{
    long i = (long)blockIdx.x * 256 + threadIdx.x;
    if (i >= total) return;
    int n = (int)(i / 36864);
    int r = (int)(i % 36864);
    int o = r / 576;
    int c = (r % 576) / 9;
    int k = r % 9;
    wt[(long)n * 36864 + ((size_t)k * 64 + c) * 64 + o] = w[i];
}

// -------------------- fp32 NCHW -> NHWC split-bf16 --------------------
__global__ void tobf_k(const float* __restrict__ in, __bf16* __restrict__ out,
                       long npl, int HW, long total)   // total = B*8*HW
{
    long idx = (long)blockIdx.x * 256 + threadIdx.x;
    if (idx >= total) return;
    int  p  = (int)(idx % HW);
    long r  = idx / HW;
    int  o8 = ((int)(r & 7)) * 8;
    int  b  = (int)(r >> 3);
    const float* src = in + ((long)b * 64 + o8) * HW + p;
    long obase = ((long)b * HW + p) * 64 + o8;
    bf16x8 hv, lv;
#pragma unroll
    for (int j = 0; j < 8; ++j) {
        float v = src[(long)j * HW];
        __bf16 h = (__bf16)v;
        hv[j] = h;
        lv[j] = (__bf16)(v - (float)h);
    }
    *(bf16x8*)(out + obase) = hv;
    *(bf16x8*)(out + npl + obase) = lv;
}

// -------------------- bilinear 2x upsample, NHWC bf16 pair, scale folded --------------------
__global__ void up2_nhwc_k(const __bf16* __restrict__ in, long inpl,
                           __bf16* __restrict__ out, long outpl,
                           int H, int W, float scale, long total)  // total = B*8*(4HW)
{
    long idx = (long)blockIdx.x * 256 + threadIdx.x;
    if (idx >= total) return;
    int o8 = ((int)(idx & 7)) * 8;
    long t = idx >> 3;
    const int W2 = 2 * W, H2 = 2 * H;
    int ox = (int)(t % W2); t /= W2;
    int oy = (int)(t % H2);
    int b  = (int)(t / H2);
    int jx = ox >> 1, jy = oy >> 1;
    int x0, y0; float wx0, wy0;
    if (ox & 1) { x0 = jx;     wx0 = 0.75f; } else { x0 = jx - 1; wx0 = 0.25f; }
    if (oy & 1) { y0 = jy;     wy0 = 0.75f; } else { y0 = jy - 1; wy0 = 0.25f; }
    int x1 = x0 + 1 > W - 1 ? W - 1 : x0 + 1;
    int y1 = y0 + 1 > H - 1 ? H - 1 : y0 + 1;
    if (x0 < 0) x0 = 0;
    if (y0 < 0) y0 = 0;
    float v00[8], v01[8], v10[8], v11[8];
    auto ld = [&](int yy, int xx, float* v) {
        long bo = ((long)(b * H + yy) * W + xx) * 64 + o8;
        bf16x8 hh = *(const bf16x8*)(in + bo);
        bf16x8 ll = *(const bf16x8*)(in + inpl + bo);
#pragma unroll
        for (int j = 0; j < 8; ++j) v[j] = (float)hh[j] + (float)ll[j];
    };
    ld(y0, x0, v00); ld(y0, x1, v01); ld(y1, x0, v10); ld(y1, x1, v11);
    float wx1 = 1.f - wx0, wy1 = 1.f - wy0;
    long obo = ((long)(b * H2 + oy) * W2 + ox) * 64 + o8;
    bf16x8 ho, lo_;
#pragma unroll
    for (int j = 0; j < 8; ++j) {
        float r = (wy0 * (wx0 * v00[j] + wx1 * v01[j]) +
                   wy1 * (wx0 * v10[j] + wx1 * v11[j])) * scale;
        __bf16 h = (__bf16)r;
        ho[j]  = h;
        lo_[j] = (__bf16)(r - (float)h);
    }
    *(bf16x8*)(out + obo) = ho;
    *(bf16x8*)(out + outpl + obo) = lo_;
}

// -------------------- conv 3x3, NHWC, barrier-free MFMA --------------------
// Grid: (W/16, B*H/4, NCHUNK). Block 256 = 4 waves; wave wid handles row
// by = blockIdx.y*4+wid, 16 consecutive x. Lane: pix=lane&15 (B col / D col),
// oct=lane>>4 (k-octet). B-frag = 16B contiguous NHWC load; taps = addr shifts.
// wt: [9][OCPAD][C] hi then lo (PER apart). D = AhBh + AhBl + AlBh.
template<int C, int NMT, int OCPAD, int OCTOT, bool RELU, bool OUTF32>
__global__ __launch_bounds__(256)
void conv_nhwc_k(const __bf16* __restrict__ in1, const __bf16* __restrict__ in2,
                 long nplane, const __bf16* __restrict__ wt, const float* __restrict__ bg,
                 void* __restrict__ outv, long onplane, int H, int W)
{
    constexpr int PER = 9 * OCPAD * C;
    const int chunk = blockIdx.z;
    const int ocblk = chunk * NMT * 16;
    const int tid = threadIdx.x;
    const int wid = __builtin_amdgcn_readfirstlane(tid >> 6);
    const int lane = tid & 63;
    const int pix = lane & 15, oct = lane >> 4;
    const int by = blockIdx.y * 4 + wid;
    const int b = by / H, y = by - b * H;
    const int x0 = blockIdx.x * 16;
    const int x = x0 + pix;

    // per-dx x offsets (clamped) + validity
    int xoff[3]; bool vxm[3];
#pragma unroll
    for (int dx = 0; dx < 3; ++dx) {
        int gx = x + dx - 1;
        bool v = (gx >= 0) & (gx < W);
        vxm[dx] = v;
        int gc = v ? gx : (gx < 0 ? 0 : W - 1);
        xoff[dx] = gc * 64;
    }

    f32x4 am[NMT], ac[NMT];
#pragma unroll
    for (int mt = 0; mt < NMT; ++mt) { am[mt] = f32x4{0,0,0,0}; ac[mt] = f32x4{0,0,0,0}; }

    const bf16x8 zv = bf16x8{};
    const int coctB = oct * 8;

    for (int c0 = 0; c0 < C; c0 += 32) {
        const __bf16* src = (C == 64 || c0 < 64) ? in1 : in2;
        const int csub = (C == 64) ? c0 : (c0 & 63);
        const __bf16* srcl = src + nplane;
        const int cofs = csub + coctB;
#pragma unroll
        for (int r = 0; r < 3; ++r) {
            int gy = y + r - 1;
            if (gy < 0 || gy >= H) continue;
            long rb = ((long)(b * H + gy) * W) * 64 + cofs;
            bf16x8 bh[3], bl[3];
#pragma unroll
            for (int dx = 0; dx < 3; ++dx) {
                bf16x8 h = *(const bf16x8*)(src  + rb + xoff[dx]);
                bf16x8 l = *(const bf16x8*)(srcl + rb + xoff[dx]);
                bh[dx] = vxm[dx] ? h : zv;
                bl[dx] = vxm[dx] ? l : zv;
            }
#pragma unroll
            for (int dx = 0; dx < 3; ++dx) {
                const int t = r * 3 + dx;
                const __bf16* wb = wt + ((long)t * OCPAD + ocblk + pix) * C + c0 + coctB;
#pragma unroll
                for (int mt = 0; mt < NMT; ++mt) {
                    bf16x8 ah = *(const bf16x8*)(wb + (long)mt * 16 * C);
                    bf16x8 al = *(const bf16x8*)(wb + (long)mt * 16 * C + PER);
                    am[mt] = __builtin_amdgcn_mfma_f32_16x16x32_bf16(ah, bh[dx], am[mt], 0, 0, 0);
                    ac[mt] = __builtin_amdgcn_mfma_f32_16x16x32_bf16(ah, bl[dx], ac[mt], 0, 0, 0);
                    ac[mt] = __builtin_amdgcn_mfma_f32_16x16x32_bf16(al, bh[dx], ac[mt], 0, 0, 0);
                }
            }
        }
    }

    // D: row(oc) = oct*4 + j (+mt*16), col(pix) = lane&15  (verified r3)
    if (OUTF32) {
        float* outf = (float*)outv;
        long opix = ((long)(b * H + y) * W + x) * (long)OCTOT;
#pragma unroll
        for (int mt = 0; mt < NMT; ++mt) {
#pragma unroll
            for (int j = 0; j < 4; ++j) {
                int oc = ocblk + mt * 16 + oct * 4 + j;
                if (oc < OCTOT) outf[opix + oc] = am[mt][j] + ac[mt][j] + bg[oc];
            }
        }
    } else {
        __bf16* outp = (__bf16*)outv;
        long opix = ((long)(b * H + y) * W + x) * 64;
#pragma unroll
        for (int mt = 0; mt < NMT; ++mt) {
            int oc0 = ocblk + mt * 16 + oct * 4;
            bf16x4 hv, lv;
#pragma unroll
            for (int j = 0; j < 4; ++j) {
                float rv = am[mt][j] + ac[mt][j] + bg[oc0 + j];
                if (RELU) rv = (rv >= 0.f) ? rv : 0.1f * rv;
                __bf16 hh = (__bf16)rv;
                hv[j] = hh;
                lv[j] = (__bf16)(rv - (float)hh);
            }
            *(bf16x4*)(outp + opix + oc0) = hv;
            *(bf16x4*)(outp + onplane + opix + oc0) = lv;
        }
    }
}

// -------------------- DCNv2, NHWC inputs --------------------
// x: NHWC bf16 pair; om: NHWC fp32 [pix][216]; Wt: [9][64][64] (k,c,o) fp32.
// 8x8 tile, 4 waves; wave wid samples groups {2wid, 2wid+1}; LDS reduction.
template<bool RELU, bool OUTF32>
__global__ __launch_bounds__(256)
void dcn_nhwc_k(const __bf16* __restrict__ x, long xnpl,
                const float* __restrict__ om,
                const float* __restrict__ Wt, const float* __restrict__ bg,
                void* __restrict__ outv, long onpl, int H, int W)
{
    const int b = blockIdx.z;
    const int tid = threadIdx.x;
    const int wid = __builtin_amdgcn_readfirstlane(tid >> 6);
    const int p = tid & 63;
    const int h = blockIdx.y * 8 + (p >> 3), w = blockIdx.x * 8 + (p & 7);

    float acc[64];
#pragma unroll
    for (int o = 0; o < 64; ++o) acc[o] = 0.f;

    const float* omp = om + ((long)(b * H + h) * W + w) * 216;

    for (int gg = 0; gg < 2; ++gg) {
        const int g = wid * 2 + gg;
        for (int k = 0; k < 9; ++k) {
            const int ch = g * 9 + k;
            float oy = omp[ch];
            float ox = omp[72 + ch];
            float mr = omp[144 + ch];
            float m  = 1.f / (1.f + expf(-mr));

            float pyf = oy + (float)(k / 3 - 1) + (float)h;
            float pxf = ox + (float)(k % 3 - 1) + (float)w;
            float fy = floorf(pyf), fx = floorf(pxf);
            float wy = pyf - fy, wx = pxf - fx;
            int y0 = (int)fy, x0 = (int)fx;
            int y1 = y0 + 1, x1 = x0 + 1;
            bool vy0 = (y0 >= 0) & (y0 < H), vy1 = (y1 >= 0) & (y1 < H);
            bool vx0 = (x0 >= 0) & (x0 < W), vx1 = (x1 >= 0) & (x1 < W);
            int y0c = y0 < 0 ? 0 : (y0 >= H ? H - 1 : y0);
            int y1c = y1 < 0 ? 0 : (y1 >= H ? H - 1 : y1);
            int x0c = x0 < 0 ? 0 : (x0 >= W ? W - 1 : x0);
            int x1c = x1 < 0 ? 0 : (x1 >= W ? W - 1 : x1);
            float w00 = (1.f - wy) * (1.f - wx) * m * ((vy0 & vx0) ? 1.f : 0.f);
            float w01 = (1.f - wy) * wx         * m * ((vy0 & vx1) ? 1.f : 0.f);
            float w10 = wy         * (1.f - wx) * m * ((vy1 & vx0) ? 1.f : 0.f);
            float w11 = wy         * wx         * m * ((vy1 & vx1) ? 1.f : 0.f);

            long i00 = ((long)(b * H + y0c) * W + x0c) * 64 + g * 8;
            long i01 = ((long)(b * H + y0c) * W + x1c) * 64 + g * 8;
            long i10 = ((long)(b * H + y1c) * W + x0c) * 64 + g * 8;
            long i11 = ((long)(b * H + y1c) * W + x1c) * 64 + g * 8;

            bf16x8 h00 = *(const bf16x8*)(x + i00), l00 = *(const bf16x8*)(x + xnpl + i00);
            bf16x8 h01 = *(const bf16x8*)(x + i01), l01 = *(const bf16x8*)(x + xnpl + i01);
            bf16x8 h10 = *(const bf16x8*)(x + i10), l10 = *(const bf16x8*)(x + xnpl + i10);
            bf16x8 h11 = *(const bf16x8*)(x + i11), l11 = *(const bf16x8*)(x + xnpl + i11);

            float s[8];
#pragma unroll
            for (int j = 0; j < 8; ++j) {
                s[j] = w00 * ((float)h00[j] + (float)l00[j])
                     + w01 * ((float)h01[j] + (float)l01[j])
                     + w10 * ((float)h10[j] + (float)l10[j])
                     + w11 * ((float)h11[j] + (float)l11[j]);
            }
#pragma unroll
            for (int cg = 0; cg < 8; ++cg) {
                const float* wko = Wt + ((long)k * 64 + g * 8 + cg) * 64;  // wave-uniform -> s_load
                float sv = s[cg];
#pragma unroll
                for (int o = 0; o < 64; ++o)
                    acc[o] = fmaf(wko[o], sv, acc[o]);
            }
        }
    }

    __shared__ float red[3][64][65];
    if (wid > 0) {
#pragma unroll
        for (int o = 0; o < 64; ++o) red[wid - 1][p][o] = acc[o];
    }
    __syncthreads();
    if (wid == 0) {
#pragma unroll
        for (int o = 0; o < 64; ++o)
            acc[o] += red[0][p][o] + red[1][p][o] + red[2][p][o];
        if (OUTF32) {
            const long HW = (long)H * W;
            float* op = (float*)outv + ((long)b * 64) * HW + (long)h * W + w;
#pragma unroll
            for (int o = 0; o < 64; ++o) {
                float r = acc[o] + bg[o];
                if (RELU) r = (r >= 0.f) ? r : 0.1f * r;
                op[(long)o * HW] = r;
            }
        } else {
            __bf16* op = (__bf16*)outv;
            long obo = ((long)(b * H + h) * W + w) * 64;
#pragma unroll
            for (int o0 = 0; o0 < 64; o0 += 8) {
                bf16x8 hv, lv;
#pragma unroll
                for (int j = 0; j < 8; ++j) {
                    float r = acc[o0 + j] + bg[o0 + j];
                    if (RELU) r = (r >= 0.f) ? r : 0.1f * r;
                    __bf16 hh = (__bf16)r;
                    hv[j] = hh;
                    lv[j] = (__bf16)(r - (float)hh);
                }
                *(bf16x8*)(op + obo + o0) = hv;
                *(bf16x8*)(op + onpl + obo + o0) = lv;
            }
        }
    }
}

// -------------------- launcher --------------------
extern "C" void kernel_launch(void* const* d_in, const int* in_sizes, int n_in,
                              void* d_out, int out_size, void* d_ws, size_t ws_size,
                              hipStream_t stream)
{
    const float* fea1_l1 = (const float*)d_in[0];
    const float* fea1_l2 = (const float*)d_in[1];
    const float* fea1_l3 = (const float*)d_in[2];
    const float* fea2_l1 = (const float*)d_in[3];
    const float* fea2_l2 = (const float*)d_in[4];
    const float* fea2_l3 = (const float*)d_in[5];
    const float* w128  = (const float*)d_in[6];
    const float* b128  = (const float*)d_in[7];
    const float* w64   = (const float*)d_in[8];
    const float* b64   = (const float*)d_in[9];
    const float* om_w  = (const float*)d_in[10];
    const float* om_b  = (const float*)d_in[11];
    const float* dcn_w = (const float*)d_in[12];
    const float* dcn_b = (const float*)d_in[13];

    const long NPL1 = 4194304, NPL2 = 1048576, NPL3 = 262144;  // elems/plane
    float* ws = (float*)d_ws;
    auto bfp = [&](long woff) -> __bf16* { return (__bf16*)(ws + woff); };

    // f32-word offsets in ws. Lifetime-audited (R5): every write interval
    // only lands on dead buffers. om region [0, 14,155,776) hosts transient
    // small tensors; A1/A2 alias om head for the L1 stage only.
    const long Z_OM   = 0;
    const long Z_A1   = 0;          // L1 T1 slot, aliases om[0,4.19M)
    const long Z_A2   = 4194304;    // L1 T1 slot, aliases om[4.19M,8.39M)
    const long Z_F1L3 = 1048576, Z_F2L3 = 1310720;
    const long Z_F1L2 = 3538944, Z_F2L2 = 4587520;
    const long Z_A2L2 = 4587520;    // L2_off_b slot (over dead F2L2; NOT over F1L2)
    const long Z_SG   = 7340032;    // L2_off   (dead before L1 om write)
    const long Z_SH   = 8388608;    // L2_fea   (dead before L1 om write)
    const long Z_SF   = 9437184;    // L3_fea
    const long Z_SE   = 9699328;    // L3_off
    const long Z_S1   = 14155776;   // safe T1 slot
    const long Z_S2   = 18350080;   // safe T1 slot
    const long Z_F1L1 = 22544384, Z_F2L1 = 26738688;
    const long Z_WB   = 30932992;   // split conv weights (bf16)
    const long Z_DT   = 32186368;   // dcn weights transposed (f32)
    // total = 32,333,824 words = 129.3 MB (< 132.3 proven safe)

    __bf16* wsp   = (__bf16*)(ws + Z_WB);
    __bf16* w128T = wsp;                       // 8 * 2*73728
    __bf16* w64T  = wsp + 1179648;             // 4 * 2*36864
    __bf16* omT   = wsp + 1474560;             // 4 * 2*129024
    float*  dT    = ws + Z_DT;
    float*  omB   = ws + Z_OM;                 // fp32 NHWC om buffer
    float*  outp  = (float*)d_out;
    __bf16* dscr  = (__bf16*)d_out;            // d_out as T1-pair scratch

    auto blocks = [](long n) { return (int)((n + 255) / 256); };

    // ---- weight transforms ----
    { long t = 8l * 73728;  wsplit_k<64,128><<<blocks(t), 256, 0, stream>>>(w128, w128T, 64, t); }
    { long t = 4l * 36864;  wsplit_k<64,64 ><<<blocks(t), 256, 0, stream>>>(w64,  w64T,  64, t); }
    { long t = 4l * 129024; wsplit_k<224,64><<<blocks(t), 256, 0, stream>>>(om_w, omT,  216, t); }
    transpose_dcnw<<<blocks(4l * 36864), 256, 0, stream>>>(dcn_w, dT, 4l * 36864);

    // ---- input conversions (before anything writes the om region) ----
    tobf_k<<<blocks(4l*8*16384), 256, 0, stream>>>(fea1_l1, bfp(Z_F1L1), NPL1, 16384, 4l*8*16384);
    tobf_k<<<blocks(4l*8*16384), 256, 0, stream>>>(fea2_l1, bfp(Z_F2L1), NPL1, 16384, 4l*8*16384);
    tobf_k<<<blocks(4l*8*4096),  256, 0, stream>>>(fea1_l2, bfp(Z_F1L2), NPL2, 4096,  4l*8*4096);
    tobf_k<<<blocks(4l*8*4096),  256, 0, stream>>>(fea2_l2, bfp(Z_F2L2), NPL2, 4096,  4l*8*4096);
    tobf_k<<<blocks(4l*8*1024),  256, 0, stream>>>(fea1_l3, bfp(Z_F1L3), NPL3, 1024,  4l*8*1024);
    tobf_k<<<blocks(4l*8*1024),  256, 0, stream>>>(fea2_l3, bfp(Z_F2L3), NPL3, 1024,  4l*8*1024);

    // ---- L3 (32x32) ----
    conv_nhwc_k<128,4,64,64,true,false><<<dim3(2,32,1), 256, 0, stream>>>(
        bfp(Z_F1L3), bfp(Z_F2L3), NPL3, w128T + 0l*147456, b128 + 0*64, bfp(Z_S1), NPL3, 32, 32);
    conv_nhwc_k<64,4,64,64,true,false><<<dim3(2,32,1), 256, 0, stream>>>(
        bfp(Z_S1), nullptr, NPL3, w64T + 0l*73728, b64 + 0*64, bfp(Z_SE), NPL3, 32, 32);
    conv_nhwc_k<64,7,224,216,false,true><<<dim3(2,32,2), 256, 0, stream>>>(
        bfp(Z_SE), nullptr, NPL3, omT + 0l*258048, om_b + 0*216, omB, 0, 32, 32);
    dcn_nhwc_k<true,false><<<dim3(4,4,4), 256, 0, stream>>>(
        bfp(Z_F1L3), NPL3, omB, dT + 0*36864, dcn_b + 0*64, bfp(Z_SF), NPL3, 32, 32);

    // ---- L2 (64x64) ----
    conv_nhwc_k<128,4,64,64,true,false><<<dim3(4,64,1), 256, 0, stream>>>(
        bfp(Z_F1L2), bfp(Z_F2L2), NPL2, w128T + 1l*147456, b128 + 1*64, bfp(Z_S1), NPL2, 64, 64);
    up2_nhwc_k<<<blocks(4l*8*4096), 256, 0, stream>>>(bfp(Z_SE), NPL3, bfp(Z_S2), NPL2, 32, 32, 2.f, 4l*8*4096);
    conv_nhwc_k<128,4,64,64,true,false><<<dim3(4,64,1), 256, 0, stream>>>(
        bfp(Z_S1), bfp(Z_S2), NPL2, w128T + 2l*147456, b128 + 2*64, bfp(Z_A2L2), NPL2, 64, 64);
    conv_nhwc_k<64,4,64,64,true,false><<<dim3(4,64,1), 256, 0, stream>>>(
        bfp(Z_A2L2), nullptr, NPL2, w64T + 1l*73728, b64 + 1*64, bfp(Z_SG), NPL2, 64, 64);
    conv_nhwc_k<64,7,224,216,false,true><<<dim3(4,64,2), 256, 0, stream>>>(
        bfp(Z_SG), nullptr, NPL2, omT + 1l*258048, om_b + 1*216, omB, 0, 64, 64);
    dcn_nhwc_k<false,false><<<dim3(8,8,4), 256, 0, stream>>>(
        bfp(Z_F1L2), NPL2, omB, dT + 1*36864, dcn_b + 1*64, bfp(Z_S1), NPL2, 64, 64);
    up2_nhwc_k<<<blocks(4l*8*4096), 256, 0, stream>>>(bfp(Z_SF), NPL3, bfp(Z_S2), NPL2, 32, 32, 1.f, 4l*8*4096);
    conv_nhwc_k<128,4,64,64,true,false><<<dim3(4,64,1), 256, 0, stream>>>(
        bfp(Z_S1), bfp(Z_S2), NPL2, w128T + 3l*147456, b128 + 3*64, bfp(Z_SH), NPL2, 64, 64);

    // ---- L1 (128x128) + cascade ----
    conv_nhwc_k<128,4,64,64,true,false><<<dim3(8,128,1), 256, 0, stream>>>(
        bfp(Z_F1L1), bfp(Z_F2L1), NPL1, w128T + 4l*147456, b128 + 4*64, bfp(Z_A1), NPL1, 128, 128);
    up2_nhwc_k<<<blocks(4l*8*16384), 256, 0, stream>>>(bfp(Z_SG), NPL2, bfp(Z_S1), NPL1, 64, 64, 2.f, 4l*8*16384);
    conv_nhwc_k<128,4,64,64,true,false><<<dim3(8,128,1), 256, 0, stream>>>(
        bfp(Z_A1), bfp(Z_S1), NPL1, w128T + 5l*147456, b128 + 5*64, bfp(Z_A2), NPL1, 128, 128);
    conv_nhwc_k<64,4,64,64,true,false><<<dim3(8,128,1), 256, 0, stream>>>(
        bfp(Z_A2), nullptr, NPL1, w64T + 2l*73728, b64 + 2*64, bfp(Z_S1), NPL1, 128, 128);   // L1_off
    up2_nhwc_k<<<blocks(4l*8*16384), 256, 0, stream>>>(bfp(Z_SH), NPL2, dscr, NPL1, 64, 64, 1.f, 4l*8*16384);
    conv_nhwc_k<64,7,224,216,false,true><<<dim3(8,128,2), 256, 0, stream>>>(
        bfp(Z_S1), nullptr, NPL1, omT + 2l*258048, om_b + 2*216, omB, 0, 128, 128);          // full om
    dcn_nhwc_k<false,false><<<dim3(16,16,4), 256, 0, stream>>>(
        bfp(Z_F1L1), NPL1, omB, dT + 2*36864, dcn_b + 2*64, bfp(Z_S2), NPL1, 128, 128);      // L1_fea_raw
    conv_nhwc_k<128,4,64,64,false,false><<<dim3(8,128,1), 256, 0, stream>>>(
        bfp(Z_S2), dscr, NPL1, w128T + 6l*147456, b128 + 6*64, bfp(Z_S1), NPL1, 128, 128);   // L1_fea (no relu)
    conv_nhwc_k<128,4,64,64,true,false><<<dim3(8,128,1), 256, 0, stream>>>(
        bfp(Z_S1), bfp(Z_F2L1), NPL1, w128T + 7l*147456, b128 + 7*64, bfp(Z_S2), NPL1, 128, 128);
    conv_nhwc_k<64,4,64,64,true,false><<<dim3(8,128,1), 256, 0, stream>>>(
        bfp(Z_S2), nullptr, NPL1, w64T + 3l*73728, b64 + 3*64, dscr, NPL1, 128, 128);        // cas_off -> d_out scratch
    conv_nhwc_k<64,7,224,216,false,true><<<dim3(8,128,2), 256, 0, stream>>>(
        dscr, nullptr, NPL1, omT + 3l*258048, om_b + 3*216, omB, 0, 128, 128);
    dcn_nhwc_k<true,true><<<dim3(16,16,4), 256, 0, stream>>>(
        bfp(Z_S1), NPL1, omB, dT + 3*36864, dcn_b + 3*64, outp, 0, 128, 128);                // final -> d_out
}